// Round 2
// baseline (127.156 us; speedup 1.0000x reference)
//
#include <hip/hip_runtime.h>
#include <hip/hip_bf16.h>
#include <stdint.h>

typedef __bf16 bf16x8 __attribute__((ext_vector_type(8)));
typedef float f32x16 __attribute__((ext_vector_type(16)));

__device__ __forceinline__ uint16_t f2bf(float f) {
    uint32_t u = __float_as_uint(f);
    u += 0x7FFFu + ((u >> 16) & 1u);   // RNE
    return (uint16_t)(u >> 16);
}

__device__ __forceinline__ float gelu_exact(float x) {
    return 0.5f * x * (1.0f + erff(x * 0.7071067811865475f));
}

// Prep: convert weights to bf16 in workspace, precompute kernel params.
__global__ void spenc_prep(const float* __restrict__ W1, const float* __restrict__ W2,
                           const float* __restrict__ means, const float* __restrict__ stds,
                           uint16_t* __restrict__ w1b, uint16_t* __restrict__ w2b,
                           float* __restrict__ prm)
{
    int idx = blockIdx.x * 256 + threadIdx.x;
    if (idx < 16384) w1b[idx] = f2bf(W1[idx]);
    if (idx < 4096)  w2b[idx] = f2bf(W2[idx]);
    if (idx < 128) {
        float s = fabsf(stds[idx]) + 0.01f;
        prm[idx]       = means[idx];
        prm[128 + idx] = 1.0f / s;
        prm[256 + idx] = 0.3989422804014327f / s;  // 1/(sqrt(2pi)*s)
    }
}

__global__ __launch_bounds__(256, 2)
void spenc_main(const float* __restrict__ coord,
                const int* __restrict__ node_type,
                const float* __restrict__ gamma_emb,
                const float* __restrict__ beta_emb,
                const float* __restrict__ b1,
                const float* __restrict__ b2,
                const uint16_t* __restrict__ w1b,
                const uint16_t* __restrict__ w2b,
                const float* __restrict__ prm,
                float* __restrict__ out,
                int N)
{
    __shared__ uint16_t AB[64 * 128];     // GK tile, then (aliased) H tile; XOR-swizzled
    __shared__ uint16_t W1s[128 * 128];   // [j][k] bf16, swizzled
    __shared__ uint16_t W2s[32 * 128];    // [h][k] bf16, swizzled
    __shared__ float sprm[384];
    __shared__ float xs[64];

    const int tid = threadIdx.x;
    const int lane = tid & 63;
    const int w = tid >> 6;
    const uint32_t NN = (uint32_t)N * (uint32_t)N;
    const uint32_t base = blockIdx.x * 64u;

    // ---- Phase A: stage weights + params; compute per-pair x ----
    for (int idx = tid; idx < 2048; idx += 256) {       // W1: 2048 x 16B
        int j = idx >> 4, c = idx & 15;
        uint4 v = ((const uint4*)w1b)[idx];
        int off = j * 256 + ((c * 16) ^ ((j & 15) << 4));
        *(uint4*)((char*)W1s + off) = v;
    }
    for (int idx = tid; idx < 512; idx += 256) {        // W2: 512 x 16B
        int j = idx >> 4, c = idx & 15;
        uint4 v = ((const uint4*)w2b)[idx];
        int off = j * 256 + ((c * 16) ^ ((j & 15) << 4));
        *(uint4*)((char*)W2s + off) = v;
    }
    for (int t = tid; t < 384; t += 256) sprm[t] = prm[t];   // FIX: cover all 384
    if (tid < 64) {
        uint32_t p = base + (uint32_t)tid;
        uint32_t b = p / NN;
        uint32_t rem = p - b * NN;
        uint32_t i = rem / (uint32_t)N;
        uint32_t jj = rem - i * (uint32_t)N;
        const float* ci = coord + ((size_t)b * N + i) * 3;
        const float* cj = coord + ((size_t)b * N + jj) * 3;
        float dx = ci[0] - cj[0];
        float dy = ci[1] - cj[1];
        float dz = ci[2] - cj[2];
        float dist = sqrtf(dx * dx + dy * dy + dz * dz);
        int nti = node_type[b * N + i];
        int ntj = node_type[b * N + jj];
        float g  = gamma_emb[nti + 2] + gamma_emb[ntj + 103];  // MAX_NODE_TYPE+3 = 103
        float be = beta_emb[nti + 2]  + beta_emb[ntj + 103];
        xs[tid] = g * dist + be;
    }
    __syncthreads();

    // ---- Phase B: gaussian basis -> bf16 GK tile (swizzled) ----
    for (int idx = tid; idx < 64 * 64; idx += 256) {
        int r = idx >> 6, kp = idx & 63;
        int k = kp * 2;
        float x = xs[r];
        float z0 = (x - sprm[k])     * sprm[128 + k];
        float z1 = (x - sprm[k + 1]) * sprm[128 + k + 1];
        float g0 = __expf(-0.5f * z0 * z0) * sprm[256 + k];
        float g1 = __expf(-0.5f * z1 * z1) * sprm[256 + k + 1];
        uint32_t pk = (uint32_t)f2bf(g0) | ((uint32_t)f2bf(g1) << 16);
        int off = r * 256 + ((kp * 4) ^ ((r & 15) << 4));
        *(uint32_t*)((char*)AB + off) = pk;
    }
    __syncthreads();

    // ---- Phase C: GEMM1  H = gelu(GK @ W1^T + b1) ----
    const int mb = w >> 1;           // wave M-block (0,1): rows mb*32..+31
    const int nb = w & 1;            // wave N-block (0,1): cols nb*64..+63
    const int l31 = lane & 31;
    const int hi = lane >> 5;        // k-group within fragment

    f32x16 acc0, acc1;
    {
        float bia0 = b1[nb * 64 + l31];
        float bia1 = b1[nb * 64 + 32 + l31];
        #pragma unroll
        for (int r = 0; r < 16; ++r) { acc0[r] = bia0; acc1[r] = bia1; }
    }
    const int arow = mb * 32 + l31;
    const int aswz = (arow & 15) << 4;
    const int jcol0 = nb * 64 + l31;
    const int jcol1 = nb * 64 + 32 + l31;
    const int jswz0 = (jcol0 & 15) << 4;
    const int jswz1 = (jcol1 & 15) << 4;
    #pragma unroll
    for (int kk = 0; kk < 8; ++kk) {
        int koff = kk * 32 + 16 * hi;
        bf16x8 a  = *(const bf16x8*)((const char*)AB  + arow  * 256 + (koff ^ aswz));
        bf16x8 b0 = *(const bf16x8*)((const char*)W1s + jcol0 * 256 + (koff ^ jswz0));
        bf16x8 b1f= *(const bf16x8*)((const char*)W1s + jcol1 * 256 + (koff ^ jswz1));
        acc0 = __builtin_amdgcn_mfma_f32_32x32x16_bf16(a, b0,  acc0, 0, 0, 0);
        acc1 = __builtin_amdgcn_mfma_f32_32x32x16_bf16(a, b1f, acc1, 0, 0, 0);
    }
    __syncthreads();   // all waves done READING GK before H overwrites AB

    #pragma unroll
    for (int r = 0; r < 16; ++r) {
        int row = mb * 32 + (r & 3) + 8 * (r >> 2) + 4 * hi;   // C/D layout (HW-verified)
        int swz = (row & 15) << 4;
        float h0 = gelu_exact(acc0[r]);
        float h1 = gelu_exact(acc1[r]);
        *(uint16_t*)((char*)AB + row * 256 + ((2 * jcol0) ^ swz)) = f2bf(h0);
        *(uint16_t*)((char*)AB + row * 256 + ((2 * jcol1) ^ swz)) = f2bf(h1);
    }
    __syncthreads();

    // ---- Phase D: GEMM2  out = H @ W2^T + b2  (waves 0,1; N=32 fits one tile) ----
    if (w < 2) {
        f32x16 acc2;
        float bia = b2[l31];
        #pragma unroll
        for (int r = 0; r < 16; ++r) acc2[r] = bia;
        const int hrow = w * 32 + l31;
        const int hswz = (hrow & 15) << 4;
        const int hcol = l31;                 // head index
        const int hcswz = (hcol & 15) << 4;
        #pragma unroll
        for (int kk = 0; kk < 8; ++kk) {
            int koff = kk * 32 + 16 * hi;
            bf16x8 a  = *(const bf16x8*)((const char*)AB  + hrow * 256 + (koff ^ hswz));
            bf16x8 bb = *(const bf16x8*)((const char*)W2s + hcol * 256 + (koff ^ hcswz));
            acc2 = __builtin_amdgcn_mfma_f32_32x32x16_bf16(a, bb, acc2, 0, 0, 0);
        }
        #pragma unroll
        for (int r = 0; r < 16; ++r) {
            int row = w * 32 + (r & 3) + 8 * (r >> 2) + 4 * hi;
            out[((size_t)(base + row)) * 32 + hcol] = acc2[r];
        }
    }
}

extern "C" void kernel_launch(void* const* d_in, const int* in_sizes, int n_in,
                              void* d_out, int out_size, void* d_ws, size_t ws_size,
                              hipStream_t stream)
{
    const float* coord     = (const float*)d_in[0];
    const int*   node_type = (const int*)d_in[1];
    const float* means     = (const float*)d_in[2];
    const float* stds      = (const float*)d_in[3];
    const float* W1        = (const float*)d_in[4];
    const float* b1        = (const float*)d_in[5];
    const float* W2        = (const float*)d_in[6];
    const float* b2        = (const float*)d_in[7];
    const float* gamma_emb = (const float*)d_in[8];
    const float* beta_emb  = (const float*)d_in[9];
    float* out = (float*)d_out;

    int BN = in_sizes[1];                                   // b*N
    uint32_t M = (uint32_t)((long long)out_size / 32);      // b*N*N pairs
    int N = (int)(M / (uint32_t)BN);                        // 512

    uint16_t* w1b = (uint16_t*)d_ws;
    uint16_t* w2b = w1b + 16384;
    float* prm = (float*)(w2b + 4096);

    spenc_prep<<<64, 256, 0, stream>>>(W1, W2, means, stds, w1b, w2b, prm);
    spenc_main<<<M / 64, 256, 0, stream>>>(coord, node_type, gamma_emb, beta_emb,
                                           b1, b2, w1b, w2b, prm, out, N);
}

// Round 3
// 90.480 us; speedup vs baseline: 1.4053x; 1.4053x over previous
//
#include <hip/hip_runtime.h>
#include <hip/hip_bf16.h>
#include <stdint.h>

typedef __bf16 bf16x8 __attribute__((ext_vector_type(8)));
typedef float f32x16 __attribute__((ext_vector_type(16)));

__device__ __forceinline__ uint16_t f2bf(float f) {
    uint32_t u = __float_as_uint(f);
    u += 0x7FFFu + ((u >> 16) & 1u);   // RNE
    return (uint16_t)(u >> 16);
}

__device__ __forceinline__ uint32_t pack2bf(float g0, float g1) {
    __bf16 a = (__bf16)g0, b = (__bf16)g1;       // compiler emits v_cvt_pk_bf16_f32
    uint16_t ua = __builtin_bit_cast(uint16_t, a);
    uint16_t ub = __builtin_bit_cast(uint16_t, b);
    return (uint32_t)ua | ((uint32_t)ub << 16);
}

__device__ __forceinline__ float gelu_tanh(float x) {
    // tanh-form GELU, NaN-free: x - x/(e+1), e = exp(2*0.79788456*(x+0.044715x^3))
    float x2 = x * x;
    float t = fmaf(x2, 0.044715f, 1.0f);
    float u2 = 1.5957691216057308f * x * t;
    float e = __expf(u2);
    return x - x * __fdividef(1.0f, e + 1.0f);
}

// Prep: convert weights to bf16 in workspace, precompute kernel params.
__global__ void spenc_prep(const float* __restrict__ W1, const float* __restrict__ W2,
                           const float* __restrict__ means, const float* __restrict__ stds,
                           uint16_t* __restrict__ w1b, uint16_t* __restrict__ w2b,
                           float* __restrict__ prm)
{
    int idx = blockIdx.x * 256 + threadIdx.x;
    if (idx < 16384) w1b[idx] = f2bf(W1[idx]);
    if (idx < 4096)  w2b[idx] = f2bf(W2[idx]);
    if (idx < 128) {
        float s = fabsf(stds[idx]) + 0.01f;
        prm[idx]       = means[idx];
        prm[128 + idx] = 1.0f / s;
        prm[256 + idx] = 0.3989422804014327f / s;  // 1/(sqrt(2pi)*s)
    }
}

__global__ __launch_bounds__(512, 4)
void spenc_main(const float* __restrict__ coord,
                const int* __restrict__ node_type,
                const float* __restrict__ gamma_emb,
                const float* __restrict__ beta_emb,
                const float* __restrict__ b1,
                const float* __restrict__ b2,
                const uint16_t* __restrict__ w1b,
                const uint16_t* __restrict__ w2b,
                const float* __restrict__ prm,
                float* __restrict__ out,
                int N)
{
    __shared__ uint16_t AB[128 * 128];    // GK tile -> (aliased) H tile; XOR-swizzled rows of 256B
    __shared__ uint16_t W1s[128 * 128];   // [j][k] bf16, swizzled
    __shared__ uint16_t W2s[32 * 128];    // [h][k] bf16, swizzled
    __shared__ float sprm[384];
    __shared__ float xs[128];

    const int tid = threadIdx.x;
    const int lane = tid & 63;
    const int w = tid >> 6;               // wave 0..7
    const uint32_t NN = (uint32_t)N * (uint32_t)N;
    const uint32_t base = blockIdx.x * 128u;

    // ---- Phase A: stage weights + params; compute per-pair x ----
    #pragma unroll
    for (int it = 0; it < 4; ++it) {                    // W1: 2048 x 16B over 512 thr
        int idx = tid + it * 512;
        int j = idx >> 4, c = idx & 15;
        uint4 v = ((const uint4*)w1b)[idx];
        int off = j * 256 + ((c * 16) ^ ((j & 15) << 4));
        *(uint4*)((char*)W1s + off) = v;
    }
    {                                                   // W2: 512 x 16B
        int j = tid >> 4, c = tid & 15;
        uint4 v = ((const uint4*)w2b)[tid];
        int off = j * 256 + ((c * 16) ^ ((j & 15) << 4));
        *(uint4*)((char*)W2s + off) = v;
    }
    if (tid < 384) sprm[tid] = prm[tid];
    if (tid < 128) {
        uint32_t p = base + (uint32_t)tid;
        uint32_t b = p / NN;
        uint32_t rem = p - b * NN;
        uint32_t i = rem / (uint32_t)N;
        uint32_t jj = rem - i * (uint32_t)N;
        const float* ci = coord + ((size_t)b * N + i) * 3;
        const float* cj = coord + ((size_t)b * N + jj) * 3;
        float dx = ci[0] - cj[0];
        float dy = ci[1] - cj[1];
        float dz = ci[2] - cj[2];
        float dist = sqrtf(dx * dx + dy * dy + dz * dz);
        int nti = node_type[b * N + i];
        int ntj = node_type[b * N + jj];
        float g  = gamma_emb[nti + 2] + gamma_emb[ntj + 103];  // MAX_NODE_TYPE+3 = 103
        float be = beta_emb[nti + 2]  + beta_emb[ntj + 103];
        xs[tid] = g * dist + be;
    }
    __syncthreads();

    // ---- Phase B: gaussian basis -> bf16 GK tile (swizzled) ----
    {
        const int kp = tid & 63;          // column pair (2 k values)
        const int rgrp = tid >> 6;        // row group 0..7
        const int k0 = kp * 2;
        const float m0 = sprm[k0],       m1 = sprm[k0 + 1];
        const float i0 = sprm[128 + k0], i1 = sprm[128 + k0 + 1];
        const float n0 = sprm[256 + k0], n1 = sprm[256 + k0 + 1];
        #pragma unroll
        for (int i = 0; i < 16; ++i) {
            int r = rgrp + (i << 3);
            float x = xs[r];
            float z0 = (x - m0) * i0;
            float z1 = (x - m1) * i1;
            float g0 = __expf(-0.5f * z0 * z0) * n0;
            float g1 = __expf(-0.5f * z1 * z1) * n1;
            int off = r * 256 + ((kp * 4) ^ ((r & 15) << 4));
            *(uint32_t*)((char*)AB + off) = pack2bf(g0, g1);
        }
    }
    __syncthreads();

    // ---- Phase C: GEMM1  H = gelu(GK @ W1^T + b1) ----
    const int mb = w >> 1;           // wave M-block 0..3: rows mb*32..+31
    const int nb = w & 1;            // wave N-block 0..1: cols nb*64..+63
    const int l31 = lane & 31;
    const int hi = lane >> 5;        // k-group within fragment

    f32x16 acc0, acc1;
    {
        float bia0 = b1[nb * 64 + l31];
        float bia1 = b1[nb * 64 + 32 + l31];
        #pragma unroll
        for (int r = 0; r < 16; ++r) { acc0[r] = bia0; acc1[r] = bia1; }
    }
    const int arow = mb * 32 + l31;
    const int aswz = (arow & 15) << 4;
    const int jcol0 = nb * 64 + l31;
    const int jcol1 = nb * 64 + 32 + l31;
    const int jswz0 = (jcol0 & 15) << 4;
    const int jswz1 = (jcol1 & 15) << 4;
    #pragma unroll
    for (int kk = 0; kk < 8; ++kk) {
        int koff = kk * 32 + 16 * hi;
        bf16x8 a  = *(const bf16x8*)((const char*)AB  + arow  * 256 + (koff ^ aswz));
        bf16x8 b0 = *(const bf16x8*)((const char*)W1s + jcol0 * 256 + (koff ^ jswz0));
        bf16x8 b1f= *(const bf16x8*)((const char*)W1s + jcol1 * 256 + (koff ^ jswz1));
        acc0 = __builtin_amdgcn_mfma_f32_32x32x16_bf16(a, b0,  acc0, 0, 0, 0);
        acc1 = __builtin_amdgcn_mfma_f32_32x32x16_bf16(a, b1f, acc1, 0, 0, 0);
    }
    __syncthreads();   // all waves done READING GK before H overwrites AB

    #pragma unroll
    for (int r = 0; r < 16; ++r) {
        int row = mb * 32 + (r & 3) + 8 * (r >> 2) + 4 * hi;   // C/D layout (HW-verified)
        int rowoff = row * 256 + ((row & 15) << 4);            // row base ^ swizzle
        float h0 = gelu_tanh(acc0[r]);
        float h1 = gelu_tanh(acc1[r]);
        *(__bf16*)((char*)AB + (rowoff ^ (2 * jcol0))) = (__bf16)h0;
        *(__bf16*)((char*)AB + (rowoff ^ (2 * jcol1))) = (__bf16)h1;
    }
    __syncthreads();

    // ---- Phase D: GEMM2  out = H @ W2^T + b2  (waves 0..3; N=32 one tile) ----
    if (w < 4) {
        f32x16 acc2;
        float bia = b2[l31];
        #pragma unroll
        for (int r = 0; r < 16; ++r) acc2[r] = bia;
        const int hrow = w * 32 + l31;
        const int hswz = (hrow & 15) << 4;
        const int hcol = l31;                 // head index
        const int hcswz = (hcol & 15) << 4;
        #pragma unroll
        for (int kk = 0; kk < 8; ++kk) {
            int koff = kk * 32 + 16 * hi;
            bf16x8 a  = *(const bf16x8*)((const char*)AB  + hrow * 256 + (koff ^ hswz));
            bf16x8 bb = *(const bf16x8*)((const char*)W2s + hcol * 256 + (koff ^ hcswz));
            acc2 = __builtin_amdgcn_mfma_f32_32x32x16_bf16(a, bb, acc2, 0, 0, 0);
        }
        #pragma unroll
        for (int r = 0; r < 16; ++r) {
            int row = w * 32 + (r & 3) + 8 * (r >> 2) + 4 * hi;
            out[((size_t)(base + row)) * 32 + hcol] = acc2[r];
        }
    }
}

extern "C" void kernel_launch(void* const* d_in, const int* in_sizes, int n_in,
                              void* d_out, int out_size, void* d_ws, size_t ws_size,
                              hipStream_t stream)
{
    const float* coord     = (const float*)d_in[0];
    const int*   node_type = (const int*)d_in[1];
    const float* means     = (const float*)d_in[2];
    const float* stds      = (const float*)d_in[3];
    const float* W1        = (const float*)d_in[4];
    const float* b1        = (const float*)d_in[5];
    const float* W2        = (const float*)d_in[6];
    const float* b2        = (const float*)d_in[7];
    const float* gamma_emb = (const float*)d_in[8];
    const float* beta_emb  = (const float*)d_in[9];
    float* out = (float*)d_out;

    int BN = in_sizes[1];                                   // b*N
    uint32_t M = (uint32_t)((long long)out_size / 32);      // b*N*N pairs
    int N = (int)(M / (uint32_t)BN);                        // 512

    uint16_t* w1b = (uint16_t*)d_ws;
    uint16_t* w2b = w1b + 16384;
    float* prm = (float*)(w2b + 4096);

    spenc_prep<<<64, 256, 0, stream>>>(W1, W2, means, stds, w1b, w2b, prm);
    spenc_main<<<M / 128, 512, 0, stream>>>(coord, node_type, gamma_emb, beta_emb,
                                            b1, b2, w1b, w2b, prm, out, N);
}